// Round 5
// baseline (129.318 us; speedup 1.0000x reference)
//
#include <hip/hip_runtime.h>

typedef __attribute__((ext_vector_type(4))) float f32x4;
typedef __attribute__((ext_vector_type(16))) float f32x16;
typedef __attribute__((ext_vector_type(8))) short bf16x8;

#define DEVFN static __device__ __forceinline__

DEVFN unsigned short f2bf(float f) {
  union { float f; unsigned u; } x; x.f = f;
  unsigned r = x.u + 0x7fffu + ((x.u >> 16) & 1u);
  return (unsigned short)(r >> 16);
}
DEVFN float bf2f(unsigned short u) {
  union { unsigned u; float f; } x; x.u = ((unsigned)u) << 16;
  return x.f;
}

DEVFN void gload_lds16(const unsigned short* g, unsigned short* l) {
  __builtin_amdgcn_global_load_lds(
      (const __attribute__((address_space(1))) unsigned int*)g,
      (__attribute__((address_space(3))) unsigned int*)l, 16, 0, 0);
}

// ---------------------------------------------------------------------------
// Fused fp32 -> bf16 cast over multiple segments.
// ---------------------------------------------------------------------------
#define NSEG 11
struct SegTable {
  const float* src[NSEG];
  unsigned short* dst[NSEG];
  int chunks[NSEG];
};

__global__ __launch_bounds__(256) void cast_f32_bf16(SegTable st) {
  int c = blockIdx.x;
  int s = 0;
  while (c >= st.chunks[s]) { c -= st.chunks[s]; ++s; }
  const float* src = st.src[s] + (long)c * 4096;
  unsigned short* dst = st.dst[s] + (long)c * 4096;
  const int t = threadIdx.x;
#pragma unroll
  for (int i = 0; i < 4; ++i) {
    float4 v = *(const float4*)(src + t * 4 + i * 1024);
    ushort4 o;
    o.x = f2bf(v.x); o.y = f2bf(v.y); o.z = f2bf(v.z); o.w = f2bf(v.w);
    *(ushort4*)(dst + t * 4 + i * 1024) = o;
  }
}

__global__ void build_zbias(const float* __restrict__ zh_b,
                            const float* __restrict__ zx_b,
                            float* __restrict__ out) {
  int i = blockIdx.x * 256 + threadIdx.x;  // grid = 12 -> 3072
  float v = 0.f;
  if (i < 1024) v = zh_b[i];
  else if (i < 2048) v = zx_b[i - 1024];
  out[i] = v;
}

// ---------------------------------------------------------------------------
// 128x128 NT bf16 GEMM body (m97 structure) for the small-K GEMMs (K=256).
// S = 16KB LDS: staging As = S[0..4096), Bs = S[4096..8192); after the
// K-loop S is reused as a 64x128 C-staging buffer for coalesced stores.
// ---------------------------------------------------------------------------
DEVFN void gemm128_body(const unsigned short* __restrict__ A,
                        const unsigned short* __restrict__ W,
                        unsigned short* __restrict__ C,
                        const float* __restrict__ bias,
                        int lda, int ldb, int ldc, int K,
                        int bx, int by, unsigned short* S) {
  unsigned short* As = S;
  unsigned short* Bs = S + 4096;
  const int m0 = by * 128, n0 = bx * 128;
  const int tid = threadIdx.x;
  const int lane = tid & 63, wid = tid >> 6;
  const int wr = wid >> 1, wc = wid & 1;

  const int srow = tid >> 2, scol = (tid & 3) * 8;
  const unsigned short* Ag0 = A + (long)(m0 + srow) * lda + scol;
  const unsigned short* Ag1 = A + (long)(m0 + 64 + srow) * lda + scol;
  const unsigned short* Wg0 = W + (long)(n0 + srow) * ldb + scol;
  const unsigned short* Wg1 = W + (long)(n0 + 64 + srow) * ldb + scol;
  unsigned short* As0 = &As[tid * 8];
  unsigned short* As1 = &As[2048 + tid * 8];
  unsigned short* Bs0 = &Bs[tid * 8];
  unsigned short* Bs1 = &Bs[2048 + tid * 8];

  const int r = lane & 15, q = lane >> 4;

  f32x4 acc[4][4];
#pragma unroll
  for (int m = 0; m < 4; ++m)
#pragma unroll
    for (int n = 0; n < 4; ++n) acc[m][n] = (f32x4)0.f;

  for (int k0 = 0; k0 < K; k0 += 32) {
    gload_lds16(Ag0 + k0, As0);
    gload_lds16(Ag1 + k0, As1);
    gload_lds16(Wg0 + k0, Bs0);
    gload_lds16(Wg1 + k0, Bs1);
    __syncthreads();

    bf16x8 af[4], bfr[4];
#pragma unroll
    for (int m = 0; m < 4; ++m)
      af[m] = *(const bf16x8*)&As[(wr * 64 + m * 16 + r) * 32 + q * 8];
#pragma unroll
    for (int n = 0; n < 4; ++n)
      bfr[n] = *(const bf16x8*)&Bs[(wc * 64 + n * 16 + r) * 32 + q * 8];
#pragma unroll
    for (int m = 0; m < 4; ++m)
#pragma unroll
      for (int n = 0; n < 4; ++n)
        acc[m][n] = __builtin_amdgcn_mfma_f32_16x16x32_bf16(af[m], bfr[n],
                                                            acc[m][n], 0, 0, 0);
    __syncthreads();
  }

  // Coalesced C store via LDS bounce: two passes of 64 rows (16KB in S).
  // Wave wr owns tile rows wr*64 + m*16 + q*4 + j, cols wc*64 + n*16 + r.
#pragma unroll
  for (int p = 0; p < 2; ++p) {
    if (p) __syncthreads();  // separate pass-0 reads from pass-1 writes
    if (wr == p) {
#pragma unroll
      for (int m = 0; m < 4; ++m)
#pragma unroll
        for (int n = 0; n < 4; ++n) {
          const int cl = wc * 64 + n * 16 + r;
          float bv = bias ? bias[n0 + cl] : 0.f;
#pragma unroll
          for (int j = 0; j < 4; ++j)
            S[(m * 16 + q * 4 + j) * 128 + cl] = f2bf(acc[m][n][j] + bv);
        }
    }
    __syncthreads();
    // 256 threads * 4 instrs * 16B = 16KB; instr j covers rows j*16..j*16+15
#pragma unroll
    for (int j = 0; j < 4; ++j) {
      const int row = j * 16 + (tid >> 4), col = (tid & 15) * 8;
      *(bf16x8*)(C + (long)(m0 + p * 64 + row) * ldc + n0 + col) =
          *(const bf16x8*)&S[row * 128 + col];
    }
  }
}

// z-GEMM: zcat = meta @ [zh_w;zx_w;zb_w]^T + bias   (M=2048,N=3072,K=256)
__global__ __launch_bounds__(256) void gemm_z(
    const unsigned short* __restrict__ A, const unsigned short* __restrict__ W,
    unsigned short* __restrict__ C, const float* __restrict__ bias) {
  __shared__ __align__(16) unsigned short S[8192];
  gemm128_body(A, W, C, bias, 256, 256, 3072, 256, blockIdx.x, blockIdx.y, S);
}

// merged d-GEMMs: 12 GEMMs (t in {h,x,b} x g in 0..3), M=2048,N=1024,K=256
__global__ __launch_bounds__(256) void gemm_d(
    const unsigned short* __restrict__ zcat, const unsigned short* __restrict__ Wd,
    unsigned short* __restrict__ dall, const float* __restrict__ db_b) {
  __shared__ __align__(16) unsigned short S[8192];
  const int zz = blockIdx.z;
  const int t = zz >> 2, g = zz & 3;
  const unsigned short* A = zcat + t * 1024 + g * 256;       // lda 3072
  const unsigned short* W = Wd + (long)zz * 262144;          // ldb 256
  unsigned short* C = dall + (long)t * 8388608 + g * 1024;   // ldc 4096
  if (t == 2) {
    gemm128_body(A, W, C, db_b + g * 1024, 3072, 256, 4096, 256,
                 blockIdx.x, blockIdx.y, S);
  } else {
    gemm128_body(A, W, C, nullptr, 3072, 256, 4096, 256,
                 blockIdx.x, blockIdx.y, S);
  }
}

// ---------------------------------------------------------------------------
// 256x256 / BK=64 / 8-wave bf16 GEMM with 32x32x16 MFMA for
//   whx[z] = {h,x}[z] @ {Wh,Wx}[z]^T ; z in {0,1}
//   M=2048, N=4096, K=1024.  (structure proven round 4)
// ---------------------------------------------------------------------------
__global__ __launch_bounds__(512, 2) void gemm256_whx(
    const unsigned short* __restrict__ Aall,   // [2][2048][1024]
    const unsigned short* __restrict__ Ball,   // [2][4096][1024]
    unsigned short* __restrict__ Call) {       // [2][2048][4096]
  __shared__ __align__(16) unsigned short As[2][2][8192];  // [buf][half][128*64]
  __shared__ __align__(16) unsigned short Bs[2][2][8192];

  const int bid = blockIdx.x;
  const int swz = (bid & 7) * 32 + (bid >> 3);
  const int z = swz >> 7;
  const int rr = swz & 127;
  const int sb = rr >> 5, wq = rr & 31;
  const int my = (sb & 1) * 4 + (wq >> 3);   // 0..7
  const int nx = (sb >> 1) * 8 + (wq & 7);   // 0..15

  const unsigned short* Ag = Aall + (long)z * 2097152 + (long)my * 262144;
  const unsigned short* Bg = Ball + (long)z * 4194304 + (long)nx * 262144;
  unsigned short* Cg = Call + (long)z * 8388608 + (long)my * 1048576 + nx * 256;

  const int tid = threadIdx.x;
  const int lane = tid & 63, wid = tid >> 6;
  const int wm = wid >> 2, wn = wid & 3;       // 2 x 4 wave grid
  const int l31 = lane & 31, l5 = lane >> 5;
  const int sw = l31 & 7;

  const int srow = tid >> 3, sslot = tid & 7;
  const int gcol = (sslot ^ (srow & 7)) * 8;
  const unsigned short* AgS = Ag + (long)srow * 1024 + gcol;
  const unsigned short* BgS = Bg + (long)srow * 1024 + gcol;

  auto stageA = [&](int buf, int half, int kt) {
    const unsigned short* s = AgS + half * 131072 + kt * 64;
    unsigned short* d = &As[buf][half][tid * 8];
    gload_lds16(s, d);
    gload_lds16(s + 65536, d + 4096);
  };
  auto stageB = [&](int buf, int half, int kt) {
    const unsigned short* s = BgS + half * 131072 + kt * 64;
    unsigned short* d = &Bs[buf][half][tid * 8];
    gload_lds16(s, d);
    gload_lds16(s + 65536, d + 4096);
  };

  int koff[4];
#pragma unroll
  for (int ks = 0; ks < 4; ++ks) koff[ks] = ((ks * 2 + l5) ^ sw) * 8;

  const int bhalf = wn >> 1;
  int brow[2];
#pragma unroll
  for (int nt = 0; nt < 2; ++nt) brow[nt] = ((wn & 1) * 64 + nt * 32 + l31) * 64;
  int arow[4];
#pragma unroll
  for (int mt = 0; mt < 4; ++mt) arow[mt] = (mt * 32 + l31) * 64;

  f32x16 acc[4][2];  // [mt][nt]
#pragma unroll
  for (int m = 0; m < 4; ++m)
#pragma unroll
    for (int n = 0; n < 2; ++n) acc[m][n] = (f32x16)0.f;

  stageA(0, 0, 0); stageB(0, 0, 0); stageA(0, 1, 0); stageB(0, 1, 0);
  stageA(1, 0, 1); stageB(1, 0, 1);
  asm volatile("s_waitcnt vmcnt(4)" ::: "memory");  // tile0 landed
  __builtin_amdgcn_s_barrier();

#pragma unroll 2
  for (int T = 0; T < 16; ++T) {
    const int buf = T & 1, nb = buf ^ 1;

    if (T < 15) { stageA(nb, 1, T + 1); stageB(nb, 1, T + 1); }

    bf16x8 bfg[2][4], af[2][4];
    const unsigned short* Ab = &As[buf][wm][0];
    {
      const unsigned short* Bb = &Bs[buf][bhalf][0];
#pragma unroll
      for (int nt = 0; nt < 2; ++nt)
#pragma unroll
        for (int ks = 0; ks < 4; ++ks)
          bfg[nt][ks] = *(const bf16x8*)(Bb + brow[nt] + koff[ks]);
#pragma unroll
      for (int m2 = 0; m2 < 2; ++m2)
#pragma unroll
        for (int ks = 0; ks < 4; ++ks)
          af[m2][ks] = *(const bf16x8*)(Ab + arow[m2] + koff[ks]);
    }

    __builtin_amdgcn_s_setprio(1);
#pragma unroll
    for (int m2 = 0; m2 < 2; ++m2)
#pragma unroll
      for (int nt = 0; nt < 2; ++nt)
#pragma unroll
        for (int ks = 0; ks < 4; ++ks)
          acc[m2][nt] = __builtin_amdgcn_mfma_f32_32x32x16_bf16(
              af[m2][ks], bfg[nt][ks], acc[m2][nt], 0, 0, 0);
    __builtin_amdgcn_s_setprio(0);

#pragma unroll
    for (int m2 = 0; m2 < 2; ++m2)
#pragma unroll
      for (int ks = 0; ks < 4; ++ks)
        af[m2][ks] = *(const bf16x8*)(Ab + arow[2 + m2] + koff[ks]);

    asm volatile("s_waitcnt lgkmcnt(0)" ::: "memory");
    __builtin_amdgcn_sched_barrier(0);
    __builtin_amdgcn_s_barrier();

    if (T < 14) { stageA(buf, 0, T + 2); stageB(buf, 0, T + 2); }

    __builtin_amdgcn_s_setprio(1);
#pragma unroll
    for (int m2 = 0; m2 < 2; ++m2)
#pragma unroll
      for (int nt = 0; nt < 2; ++nt)
#pragma unroll
        for (int ks = 0; ks < 4; ++ks)
          acc[2 + m2][nt] = __builtin_amdgcn_mfma_f32_32x32x16_bf16(
              af[m2][ks], bfg[nt][ks], acc[2 + m2][nt], 0, 0, 0);
    __builtin_amdgcn_s_setprio(0);

    if (T < 14) {
      asm volatile("s_waitcnt vmcnt(4)" ::: "memory");
      __builtin_amdgcn_s_barrier();
    } else if (T == 14) {
      asm volatile("s_waitcnt vmcnt(0)" ::: "memory");
      __builtin_amdgcn_s_barrier();
    }
  }

  // Coalesced C store via LDS bounce: As region (64KB) holds 128x256 bf16.
  // Pass p stages rows [p*128, p*128+128) (owned by waves wm==p).
  unsigned short* Cs = &As[0][0][0];
#pragma unroll
  for (int p = 0; p < 2; ++p) {
    __syncthreads();
    if (wm == p) {
#pragma unroll
      for (int mt = 0; mt < 4; ++mt)
#pragma unroll
        for (int nt = 0; nt < 2; ++nt) {
          const int col = wn * 64 + nt * 32 + l31;
#pragma unroll
          for (int reg = 0; reg < 16; ++reg) {
            const int rl = mt * 32 + (reg & 3) + 8 * (reg >> 2) + 4 * l5;
            Cs[rl * 256 + col] = f2bf(acc[mt][nt][reg]);
          }
        }
    }
    __syncthreads();
    // 512 threads * 8 instrs * 16B = 64KB; instr j covers rows j*16..j*16+15
#pragma unroll
    for (int j = 0; j < 8; ++j) {
      const int row = j * 16 + (tid >> 5), col = (tid & 31) * 8;
      *(bf16x8*)(Cg + (long)(p * 128 + row) * 4096 + col) =
          *(const bf16x8*)&Cs[row * 256 + col];
    }
  }
}

// ---------------------------------------------------------------------------
// Epilogue: y = d_h*wh + d_x*wx + d_b ; per-(b,g) LayerNorm ; LSTM gates.
// ---------------------------------------------------------------------------
DEVFN void ld4bf(const unsigned short* p, float* o) {
  ushort4 v = *(const ushort4*)p;
  o[0] = bf2f(v.x); o[1] = bf2f(v.y); o[2] = bf2f(v.z); o[3] = bf2f(v.w);
}

__global__ __launch_bounds__(256) void epilogue_kernel(
    const unsigned short* __restrict__ d_all,   // [3][2048][4096] bf16
    const unsigned short* __restrict__ whx,     // [2][2048][4096] bf16
    const float* __restrict__ c_in,             // [2048][1024]
    const float* __restrict__ ln_w, const float* __restrict__ ln_b,
    float* __restrict__ out) {
  const long b = blockIdx.x;
  const int t = threadIdx.x;
  const int lane = t & 63, wid = t >> 6;

  const unsigned short* dh = d_all + b * 4096;
  const unsigned short* dx = d_all + 8388608L + b * 4096;
  const unsigned short* db = d_all + 16777216L + b * 4096;
  const unsigned short* wh = whx + b * 4096;
  const unsigned short* wx = whx + 8388608L + b * 4096;

  __shared__ float redS[4][4], redQ[4][4];
  float y[4][4];

#pragma unroll
  for (int g = 0; g < 4; ++g) {
    const int base = g * 1024 + t * 4;
    float fdh[4], fdx[4], fdb[4], fwh[4], fwx[4];
    ld4bf(dh + base, fdh);
    ld4bf(dx + base, fdx);
    ld4bf(db + base, fdb);
    ld4bf(wh + base, fwh);
    ld4bf(wx + base, fwx);
    float s = 0.f, sq = 0.f;
#pragma unroll
    for (int j = 0; j < 4; ++j) {
      float v = fdh[j] * fwh[j] + fdx[j] * fwx[j] + fdb[j];
      y[g][j] = v;
      s += v;
      sq += v * v;
    }
#pragma unroll
    for (int off = 32; off; off >>= 1) {
      s += __shfl_down(s, off);
      sq += __shfl_down(sq, off);
    }
    if (lane == 0) { redS[g][wid] = s; redQ[g][wid] = sq; }
  }
  __syncthreads();

  float yn[4][4];
#pragma unroll
  for (int g = 0; g < 4; ++g) {
    float S = redS[g][0] + redS[g][1] + redS[g][2] + redS[g][3];
    float SQ = redQ[g][0] + redQ[g][1] + redQ[g][2] + redQ[g][3];
    float mu = S * (1.f / 1024.f);
    float var = SQ * (1.f / 1024.f) - mu * mu;
    float rs = rsqrtf(var + 1e-5f);
    const int base = g * 1024 + t * 4;
    float4 lw = *(const float4*)(ln_w + base);
    float4 lb = *(const float4*)(ln_b + base);
    yn[g][0] = (y[g][0] - mu) * rs * lw.x + lb.x;
    yn[g][1] = (y[g][1] - mu) * rs * lw.y + lb.y;
    yn[g][2] = (y[g][2] - mu) * rs * lw.z + lb.z;
    yn[g][3] = (y[g][3] - mu) * rs * lw.w + lb.w;
  }

  float4 cp = *(const float4*)(c_in + b * 1024 + t * 4);
  float cin[4] = {cp.x, cp.y, cp.z, cp.w};
  float hn[4], cn[4];
#pragma unroll
  for (int j = 0; j < 4; ++j) {
    float ii = yn[0][j], ff = yn[1][j], gg = yn[2][j], oo = yn[3][j];
    float si = 1.f / (1.f + expf(-ii));
    float sf = 1.f / (1.f + expf(-ff));
    float so = 1.f / (1.f + expf(-oo));
    float cnj = sf * cin[j] + si * tanhf(gg);
    cn[j] = cnj;
    hn[j] = so * tanhf(cnj);
  }
  float4 ho = {hn[0], hn[1], hn[2], hn[3]};
  float4 co = {cn[0], cn[1], cn[2], cn[3]};
  *(float4*)(out + b * 1024 + t * 4) = ho;
  *(float4*)(out + 2097152L + b * 1024 + t * 4) = co;
}

// ---------------------------------------------------------------------------
extern "C" void kernel_launch(void* const* d_in, const int* in_sizes, int n_in,
                              void* d_out, int out_size, void* d_ws,
                              size_t ws_size, hipStream_t stream) {
  const float* src_x = (const float*)d_in[0];
  const float* h_in  = (const float*)d_in[1];
  const float* c_in  = (const float*)d_in[2];
  const float* meta  = (const float*)d_in[3];
  const float* zh_w  = (const float*)d_in[4];
  const float* zh_b  = (const float*)d_in[5];
  const float* zx_w  = (const float*)d_in[6];
  const float* zx_b  = (const float*)d_in[7];
  const float* zb_w  = (const float*)d_in[8];
  const float* dh_w  = (const float*)d_in[9];
  const float* dx_w  = (const float*)d_in[10];
  const float* db_w  = (const float*)d_in[11];
  const float* db_b  = (const float*)d_in[12];
  const float* w_h   = (const float*)d_in[13];
  const float* w_x   = (const float*)d_in[14];
  const float* ln_w  = (const float*)d_in[15];
  const float* ln_b  = (const float*)d_in[16];

  char* ws = (char*)d_ws;
  unsigned short* h_bf    = (unsigned short*)(ws + 0);          //  4 MB
  unsigned short* x_bf    = (unsigned short*)(ws + 4194304);    //  4 MB (contig)
  unsigned short* meta_bf = (unsigned short*)(ws + 8388608);    //  1 MB
  unsigned short* Wh      = (unsigned short*)(ws + 9437184);    //  8 MB
  unsigned short* Wx      = (unsigned short*)(ws + 17825792);   //  8 MB (contig)
  unsigned short* Wz      = (unsigned short*)(ws + 26214400);   //  1.5 MB
  unsigned short* Wd      = (unsigned short*)(ws + 27787264);   //  6 MB
  unsigned short* zcat    = (unsigned short*)(ws + 34078720);   // 12 MB
  unsigned short* dall    = (unsigned short*)(ws + 46661632);   // 48 MB
  unsigned short* whx     = (unsigned short*)(ws + 96993280);   // 32 MB
  float* zcat_b           = (float*)(ws + 130547712);           // 12 KB
  if (ws_size < 130560000) return;

  SegTable st;
  int i = 0, total = 0;
  auto add = [&](const float* s, unsigned short* d, int n) {
    st.src[i] = s; st.dst[i] = d; st.chunks[i] = n / 4096;
    total += n / 4096; ++i;
  };
  add(h_in, h_bf, 2048 * 1024);
  add(src_x, x_bf, 2048 * 1024);
  add(meta, meta_bf, 2048 * 256);
  add(w_h, Wh, 4096 * 1024);
  add(w_x, Wx, 4096 * 1024);
  add(zh_w, Wz, 1024 * 256);
  add(zx_w, Wz + 262144, 1024 * 256);
  add(zb_w, Wz + 524288, 1024 * 256);
  add(dh_w, Wd, 4 * 1024 * 256);
  add(dx_w, Wd + 1048576, 4 * 1024 * 256);
  add(db_w, Wd + 2097152, 4 * 1024 * 256);
  cast_f32_bf16<<<total, 256, 0, stream>>>(st);
  build_zbias<<<12, 256, 0, stream>>>(zh_b, zx_b, zcat_b);

  // zcat = meta @ [zh_w;zx_w;zb_w]^T + bias   (M=2048,N=3072,K=256)
  gemm_z<<<dim3(24, 16, 1), 256, 0, stream>>>(meta_bf, Wz, zcat, zcat_b);

  // all 12 d-GEMMs in one dispatch
  gemm_d<<<dim3(8, 16, 12), 256, 0, stream>>>(zcat, Wd, dall, db_b);

  // wh/wx via 256^2 kernel (grid exactly 256 blocks)
  gemm256_whx<<<256, 512, 0, stream>>>(h_bf, Wh, whx);

  // fused LN + gates
  epilogue_kernel<<<2048, 256, 0, stream>>>(dall, whx, c_in, ln_w, ln_b,
                                            (float*)d_out);
}

// Round 6
// 121.926 us; speedup vs baseline: 1.0606x; 1.0606x over previous
//
#include <hip/hip_runtime.h>

typedef __attribute__((ext_vector_type(4))) float f32x4;
typedef __attribute__((ext_vector_type(16))) float f32x16;
typedef __attribute__((ext_vector_type(8))) short bf16x8;

#define DEVFN static __device__ __forceinline__

DEVFN unsigned short f2bf(float f) {
  union { float f; unsigned u; } x; x.f = f;
  unsigned r = x.u + 0x7fffu + ((x.u >> 16) & 1u);
  return (unsigned short)(r >> 16);
}
DEVFN float bf2f(unsigned short u) {
  union { unsigned u; float f; } x; x.u = ((unsigned)u) << 16;
  return x.f;
}

DEVFN void gload_lds16(const unsigned short* g, unsigned short* l) {
  __builtin_amdgcn_global_load_lds(
      (const __attribute__((address_space(1))) unsigned int*)g,
      (__attribute__((address_space(3))) unsigned int*)l, 16, 0, 0);
}

// ---------------------------------------------------------------------------
// Fused fp32 -> bf16 cast over multiple segments.
// ---------------------------------------------------------------------------
#define NSEG 8
struct SegTable {
  const float* src[NSEG];
  unsigned short* dst[NSEG];
  int chunks[NSEG];
};

__global__ __launch_bounds__(256) void cast_f32_bf16(SegTable st) {
  int c = blockIdx.x;
  int s = 0;
  while (c >= st.chunks[s]) { c -= st.chunks[s]; ++s; }
  const float* src = st.src[s] + (long)c * 4096;
  unsigned short* dst = st.dst[s] + (long)c * 4096;
  const int t = threadIdx.x;
#pragma unroll
  for (int i = 0; i < 4; ++i) {
    float4 v = *(const float4*)(src + t * 4 + i * 1024);
    ushort4 o;
    o.x = f2bf(v.x); o.y = f2bf(v.y); o.z = f2bf(v.z); o.w = f2bf(v.w);
    *(ushort4*)(dst + t * 4 + i * 1024) = o;
  }
}

// ---------------------------------------------------------------------------
// Transpose-cast z-weights: WzT[zz][k][j] = zw_t[g*256+j][k] (bf16), zz=t*4+g.
// grid dim3(4,4,12), 256 thr; 64x64 tile per block.
// ---------------------------------------------------------------------------
__global__ __launch_bounds__(256) void tcast_z(
    const float* __restrict__ zh_w, const float* __restrict__ zx_w,
    const float* __restrict__ zb_w, unsigned short* __restrict__ WzT) {
  const int zz = blockIdx.z;
  const int t = zz >> 2, g = zz & 3;
  const float* src =
      (t == 0 ? zh_w : (t == 1 ? zx_w : zb_w)) + (long)g * 65536;
  unsigned short* dst = WzT + (long)zz * 65536;
  const int j0 = blockIdx.x * 64, k0 = blockIdx.y * 64;
  __shared__ float T[64][65];
  const int tid = threadIdx.x;
  const int jr = tid >> 2, kc = (tid & 3) * 16;
#pragma unroll
  for (int i = 0; i < 4; ++i) {
    float4 v = *(const float4*)(src + (long)(j0 + jr) * 256 + k0 + kc + i * 4);
    T[jr][kc + i * 4 + 0] = v.x;
    T[jr][kc + i * 4 + 1] = v.y;
    T[jr][kc + i * 4 + 2] = v.z;
    T[jr][kc + i * 4 + 3] = v.w;
  }
  __syncthreads();
  const int kr = tid >> 2, jc = (tid & 3) * 16;
  unsigned short tmp[16];
#pragma unroll
  for (int i = 0; i < 16; ++i) tmp[i] = f2bf(T[jc + i][kr]);
  *(bf16x8*)(dst + (long)(k0 + kr) * 256 + j0 + jc) = *(bf16x8*)&tmp[0];
  *(bf16x8*)(dst + (long)(k0 + kr) * 256 + j0 + jc + 8) = *(bf16x8*)&tmp[8];
}

// ---------------------------------------------------------------------------
// F bias: F[0/1][g][h] = sum_j z_b[t][g*256+j] * dw_t[g][h][j] (fp32 exact);
// F[2] = db_b. grid 132 blocks x 256 thr.
// ---------------------------------------------------------------------------
__global__ __launch_bounds__(256) void fbias_kernel(
    const float* __restrict__ zh_b, const float* __restrict__ zx_b,
    const float* __restrict__ db_b, const float* __restrict__ dh_w,
    const float* __restrict__ dx_w, float* __restrict__ F) {
  if (blockIdx.x >= 128) {  // copy db_b -> F[2]
    const int idx = (blockIdx.x - 128) * 1024 + threadIdx.x * 4;
    *(float4*)(F + 8192 + idx) = *(const float4*)(db_b + idx);
    return;
  }
  const int wgid = blockIdx.x * 4 + (threadIdx.x >> 6);  // 0..511
  const int lane = threadIdx.x & 63;
  const int t = wgid >> 8, g = (wgid >> 6) & 3, hbase = (wgid & 63) * 16;
  const float* zb = (t == 0 ? zh_b : zx_b) + g * 256;
  const float* dw = (t == 0 ? dh_w : dx_w) + (long)g * 262144;
  float4 zv = *(const float4*)(zb + lane * 4);
#pragma unroll
  for (int i = 0; i < 16; ++i) {
    const int h = hbase + i;
    float4 wv = *(const float4*)(dw + (long)h * 256 + lane * 4);
    float s = zv.x * wv.x + zv.y * wv.y + zv.z * wv.z + zv.w * wv.w;
#pragma unroll
    for (int off = 32; off; off >>= 1) s += __shfl_down(s, off);
    if (lane == 0) F[(t * 4 + g) * 1024 + h] = s;
  }
}

// ---------------------------------------------------------------------------
// 128x128 NT bf16 GEMM body (m97 structure, round-4 proven).
// ---------------------------------------------------------------------------
DEVFN void gemm128_body(const unsigned short* __restrict__ A,
                        const unsigned short* __restrict__ W,
                        unsigned short* __restrict__ C,
                        const float* __restrict__ bias,
                        int lda, int ldb, int ldc, int K,
                        int bx, int by,
                        unsigned short* As, unsigned short* Bs) {
  const int m0 = by * 128, n0 = bx * 128;
  const int tid = threadIdx.x;
  const int lane = tid & 63, wid = tid >> 6;
  const int wr = wid >> 1, wc = wid & 1;

  const int srow = tid >> 2, scol = (tid & 3) * 8;
  const unsigned short* Ag0 = A + (long)(m0 + srow) * lda + scol;
  const unsigned short* Ag1 = A + (long)(m0 + 64 + srow) * lda + scol;
  const unsigned short* Wg0 = W + (long)(n0 + srow) * ldb + scol;
  const unsigned short* Wg1 = W + (long)(n0 + 64 + srow) * ldb + scol;
  unsigned short* As0 = &As[tid * 8];
  unsigned short* As1 = &As[2048 + tid * 8];
  unsigned short* Bs0 = &Bs[tid * 8];
  unsigned short* Bs1 = &Bs[2048 + tid * 8];

  const int r = lane & 15, q = lane >> 4;

  f32x4 acc[4][4];
#pragma unroll
  for (int m = 0; m < 4; ++m)
#pragma unroll
    for (int n = 0; n < 4; ++n) acc[m][n] = (f32x4)0.f;

  for (int k0 = 0; k0 < K; k0 += 32) {
    gload_lds16(Ag0 + k0, As0);
    gload_lds16(Ag1 + k0, As1);
    gload_lds16(Wg0 + k0, Bs0);
    gload_lds16(Wg1 + k0, Bs1);
    __syncthreads();

    bf16x8 af[4], bfr[4];
#pragma unroll
    for (int m = 0; m < 4; ++m)
      af[m] = *(const bf16x8*)&As[(wr * 64 + m * 16 + r) * 32 + q * 8];
#pragma unroll
    for (int n = 0; n < 4; ++n)
      bfr[n] = *(const bf16x8*)&Bs[(wc * 64 + n * 16 + r) * 32 + q * 8];
#pragma unroll
    for (int m = 0; m < 4; ++m)
#pragma unroll
      for (int n = 0; n < 4; ++n)
        acc[m][n] = __builtin_amdgcn_mfma_f32_16x16x32_bf16(af[m], bfr[n],
                                                            acc[m][n], 0, 0, 0);
    __syncthreads();
  }

#pragma unroll
  for (int m = 0; m < 4; ++m) {
    const int row = m0 + wr * 64 + m * 16 + q * 4;
#pragma unroll
    for (int n = 0; n < 4; ++n) {
      const int col = n0 + wc * 64 + n * 16 + r;
      float bv = bias ? bias[col] : 0.f;
#pragma unroll
      for (int j = 0; j < 4; ++j) {
        float v = acc[m][n][j] + bv;
        C[(long)(row + j) * ldc + col] = f2bf(v);
      }
    }
  }
}

// E-GEMM: E[zz] (1024h x 256k) = Wd[zz] (1024x256 over j) @ WzT[zz]^T-form
__global__ __launch_bounds__(256) void gemm_e(
    const unsigned short* __restrict__ Wd, const unsigned short* __restrict__ WzT,
    unsigned short* __restrict__ E) {
  __shared__ __align__(16) unsigned short As[4096];
  __shared__ __align__(16) unsigned short Bs[4096];
  const int zz = blockIdx.z;
  gemm128_body(Wd + (long)zz * 262144, WzT + (long)zz * 65536,
               E + (long)zz * 262144, nullptr,
               256, 256, 256, 256, blockIdx.x, blockIdx.y, As, Bs);
}

// d-GEMMs direct: dall[t][:, g*1024..] = meta @ E[zz]^T-form + F[zz]
__global__ __launch_bounds__(256) void gemm_d(
    const unsigned short* __restrict__ meta_bf, const unsigned short* __restrict__ E,
    unsigned short* __restrict__ dall, const float* __restrict__ F) {
  __shared__ __align__(16) unsigned short As[4096];
  __shared__ __align__(16) unsigned short Bs[4096];
  const int zz = blockIdx.z;
  unsigned short* C = dall + (long)(zz >> 2) * 8388608 + (zz & 3) * 1024;
  gemm128_body(meta_bf, E + (long)zz * 262144, C, F + zz * 1024,
               256, 256, 4096, 256, blockIdx.x, blockIdx.y, As, Bs);
}

// ---------------------------------------------------------------------------
// 256x256 / BK=64 / 8-wave bf16 GEMM with 32x32x16 MFMA (round-4 proven).
// ---------------------------------------------------------------------------
__global__ __launch_bounds__(512, 2) void gemm256_whx(
    const unsigned short* __restrict__ Aall,   // [2][2048][1024]
    const unsigned short* __restrict__ Ball,   // [2][4096][1024]
    unsigned short* __restrict__ Call) {       // [2][2048][4096]
  __shared__ __align__(16) unsigned short As[2][2][8192];  // [buf][half][128*64]
  __shared__ __align__(16) unsigned short Bs[2][2][8192];

  const int bid = blockIdx.x;
  const int swz = (bid & 7) * 32 + (bid >> 3);
  const int z = swz >> 7;
  const int rr = swz & 127;
  const int sb = rr >> 5, wq = rr & 31;
  const int my = (sb & 1) * 4 + (wq >> 3);   // 0..7
  const int nx = (sb >> 1) * 8 + (wq & 7);   // 0..15

  const unsigned short* Ag = Aall + (long)z * 2097152 + (long)my * 262144;
  const unsigned short* Bg = Ball + (long)z * 4194304 + (long)nx * 262144;
  unsigned short* Cg = Call + (long)z * 8388608 + (long)my * 1048576 + nx * 256;

  const int tid = threadIdx.x;
  const int lane = tid & 63, wid = tid >> 6;
  const int wm = wid >> 2, wn = wid & 3;       // 2 x 4 wave grid
  const int l31 = lane & 31, l5 = lane >> 5;
  const int sw = l31 & 7;

  const int srow = tid >> 3, sslot = tid & 7;
  const int gcol = (sslot ^ (srow & 7)) * 8;
  const unsigned short* AgS = Ag + (long)srow * 1024 + gcol;
  const unsigned short* BgS = Bg + (long)srow * 1024 + gcol;

  auto stageA = [&](int buf, int half, int kt) {
    const unsigned short* s = AgS + half * 131072 + kt * 64;
    unsigned short* d = &As[buf][half][tid * 8];
    gload_lds16(s, d);
    gload_lds16(s + 65536, d + 4096);
  };
  auto stageB = [&](int buf, int half, int kt) {
    const unsigned short* s = BgS + half * 131072 + kt * 64;
    unsigned short* d = &Bs[buf][half][tid * 8];
    gload_lds16(s, d);
    gload_lds16(s + 65536, d + 4096);
  };

  int koff[4];
#pragma unroll
  for (int ks = 0; ks < 4; ++ks) koff[ks] = ((ks * 2 + l5) ^ sw) * 8;

  const int bhalf = wn >> 1;
  int brow[2];
#pragma unroll
  for (int nt = 0; nt < 2; ++nt) brow[nt] = ((wn & 1) * 64 + nt * 32 + l31) * 64;
  int arow[4];
#pragma unroll
  for (int mt = 0; mt < 4; ++mt) arow[mt] = (mt * 32 + l31) * 64;

  f32x16 acc[4][2];  // [mt][nt]
#pragma unroll
  for (int m = 0; m < 4; ++m)
#pragma unroll
    for (int n = 0; n < 2; ++n) acc[m][n] = (f32x16)0.f;

  stageA(0, 0, 0); stageB(0, 0, 0); stageA(0, 1, 0); stageB(0, 1, 0);
  stageA(1, 0, 1); stageB(1, 0, 1);
  asm volatile("s_waitcnt vmcnt(4)" ::: "memory");  // tile0 landed
  __builtin_amdgcn_s_barrier();

#pragma unroll 2
  for (int T = 0; T < 16; ++T) {
    const int buf = T & 1, nb = buf ^ 1;

    if (T < 15) { stageA(nb, 1, T + 1); stageB(nb, 1, T + 1); }

    bf16x8 bfg[2][4], af[2][4];
    const unsigned short* Ab = &As[buf][wm][0];
    {
      const unsigned short* Bb = &Bs[buf][bhalf][0];
#pragma unroll
      for (int nt = 0; nt < 2; ++nt)
#pragma unroll
        for (int ks = 0; ks < 4; ++ks)
          bfg[nt][ks] = *(const bf16x8*)(Bb + brow[nt] + koff[ks]);
#pragma unroll
      for (int m2 = 0; m2 < 2; ++m2)
#pragma unroll
        for (int ks = 0; ks < 4; ++ks)
          af[m2][ks] = *(const bf16x8*)(Ab + arow[m2] + koff[ks]);
    }

    __builtin_amdgcn_s_setprio(1);
#pragma unroll
    for (int m2 = 0; m2 < 2; ++m2)
#pragma unroll
      for (int nt = 0; nt < 2; ++nt)
#pragma unroll
        for (int ks = 0; ks < 4; ++ks)
          acc[m2][nt] = __builtin_amdgcn_mfma_f32_32x32x16_bf16(
              af[m2][ks], bfg[nt][ks], acc[m2][nt], 0, 0, 0);
    __builtin_amdgcn_s_setprio(0);

#pragma unroll
    for (int m2 = 0; m2 < 2; ++m2)
#pragma unroll
      for (int ks = 0; ks < 4; ++ks)
        af[m2][ks] = *(const bf16x8*)(Ab + arow[2 + m2] + koff[ks]);

    asm volatile("s_waitcnt lgkmcnt(0)" ::: "memory");
    __builtin_amdgcn_sched_barrier(0);
    __builtin_amdgcn_s_barrier();

    if (T < 14) { stageA(buf, 0, T + 2); stageB(buf, 0, T + 2); }

    __builtin_amdgcn_s_setprio(1);
#pragma unroll
    for (int m2 = 0; m2 < 2; ++m2)
#pragma unroll
      for (int nt = 0; nt < 2; ++nt)
#pragma unroll
        for (int ks = 0; ks < 4; ++ks)
          acc[2 + m2][nt] = __builtin_amdgcn_mfma_f32_32x32x16_bf16(
              af[m2][ks], bfg[nt][ks], acc[2 + m2][nt], 0, 0, 0);
    __builtin_amdgcn_s_setprio(0);

    if (T < 14) {
      asm volatile("s_waitcnt vmcnt(4)" ::: "memory");
      __builtin_amdgcn_s_barrier();
    } else if (T == 14) {
      asm volatile("s_waitcnt vmcnt(0)" ::: "memory");
      __builtin_amdgcn_s_barrier();
    }
  }

  // epilogue: 32x32 C/D layout: col = lane&31, row = (reg&3)+8*(reg>>2)+4*l5
#pragma unroll
  for (int mt = 0; mt < 4; ++mt) {
#pragma unroll
    for (int nt = 0; nt < 2; ++nt) {
      const int rb = wm * 128 + mt * 32 + 4 * l5;
      const int cb = wn * 64 + nt * 32 + l31;
#pragma unroll
      for (int reg = 0; reg < 16; ++reg) {
        const int row = rb + (reg & 3) + 8 * (reg >> 2);
        Cg[(long)row * 4096 + cb] = f2bf(acc[mt][nt][reg]);
      }
    }
  }
}

// ---------------------------------------------------------------------------
// Epilogue: y = d_h*wh + d_x*wx + d_b ; per-(b,g) LayerNorm ; LSTM gates.
// ---------------------------------------------------------------------------
DEVFN void ld4bf(const unsigned short* p, float* o) {
  ushort4 v = *(const ushort4*)p;
  o[0] = bf2f(v.x); o[1] = bf2f(v.y); o[2] = bf2f(v.z); o[3] = bf2f(v.w);
}

__global__ __launch_bounds__(256) void epilogue_kernel(
    const unsigned short* __restrict__ d_all,   // [3][2048][4096] bf16
    const unsigned short* __restrict__ whx,     // [2][2048][4096] bf16
    const float* __restrict__ c_in,             // [2048][1024]
    const float* __restrict__ ln_w, const float* __restrict__ ln_b,
    float* __restrict__ out) {
  const long b = blockIdx.x;
  const int t = threadIdx.x;
  const int lane = t & 63, wid = t >> 6;

  const unsigned short* dh = d_all + b * 4096;
  const unsigned short* dx = d_all + 8388608L + b * 4096;
  const unsigned short* db = d_all + 16777216L + b * 4096;
  const unsigned short* wh = whx + b * 4096;
  const unsigned short* wx = whx + 8388608L + b * 4096;

  __shared__ float redS[4][4], redQ[4][4];
  float y[4][4];

#pragma unroll
  for (int g = 0; g < 4; ++g) {
    const int base = g * 1024 + t * 4;
    float fdh[4], fdx[4], fdb[4], fwh[4], fwx[4];
    ld4bf(dh + base, fdh);
    ld4bf(dx + base, fdx);
    ld4bf(db + base, fdb);
    ld4bf(wh + base, fwh);
    ld4bf(wx + base, fwx);
    float s = 0.f, sq = 0.f;
#pragma unroll
    for (int j = 0; j < 4; ++j) {
      float v = fdh[j] * fwh[j] + fdx[j] * fwx[j] + fdb[j];
      y[g][j] = v;
      s += v;
      sq += v * v;
    }
#pragma unroll
    for (int off = 32; off; off >>= 1) {
      s += __shfl_down(s, off);
      sq += __shfl_down(sq, off);
    }
    if (lane == 0) { redS[g][wid] = s; redQ[g][wid] = sq; }
  }
  __syncthreads();

  float yn[4][4];
#pragma unroll
  for (int g = 0; g < 4; ++g) {
    float S = redS[g][0] + redS[g][1] + redS[g][2] + redS[g][3];
    float SQ = redQ[g][0] + redQ[g][1] + redQ[g][2] + redQ[g][3];
    float mu = S * (1.f / 1024.f);
    float var = SQ * (1.f / 1024.f) - mu * mu;
    float rs = rsqrtf(var + 1e-5f);
    const int base = g * 1024 + t * 4;
    float4 lw = *(const float4*)(ln_w + base);
    float4 lb = *(const float4*)(ln_b + base);
    yn[g][0] = (y[g][0] - mu) * rs * lw.x + lb.x;
    yn[g][1] = (y[g][1] - mu) * rs * lw.y + lb.y;
    yn[g][2] = (y[g][2] - mu) * rs * lw.z + lb.z;
    yn[g][3] = (y[g][3] - mu) * rs * lw.w + lb.w;
  }

  float4 cp = *(const float4*)(c_in + b * 1024 + t * 4);
  float cin[4] = {cp.x, cp.y, cp.z, cp.w};
  float hn[4], cn[4];
#pragma unroll
  for (int j = 0; j < 4; ++j) {
    float ii = yn[0][j], ff = yn[1][j], gg = yn[2][j], oo = yn[3][j];
    float si = 1.f / (1.f + expf(-ii));
    float sf = 1.f / (1.f + expf(-ff));
    float so = 1.f / (1.f + expf(-oo));
    float cnj = sf * cin[j] + si * tanhf(gg);
    cn[j] = cnj;
    hn[j] = so * tanhf(cnj);
  }
  float4 ho = {hn[0], hn[1], hn[2], hn[3]};
  float4 co = {cn[0], cn[1], cn[2], cn[3]};
  *(float4*)(out + b * 1024 + t * 4) = ho;
  *(float4*)(out + 2097152L + b * 1024 + t * 4) = co;
}

// ---------------------------------------------------------------------------
extern "C" void kernel_launch(void* const* d_in, const int* in_sizes, int n_in,
                              void* d_out, int out_size, void* d_ws,
                              size_t ws_size, hipStream_t stream) {
  const float* src_x = (const float*)d_in[0];
  const float* h_in  = (const float*)d_in[1];
  const float* c_in  = (const float*)d_in[2];
  const float* meta  = (const float*)d_in[3];
  const float* zh_w  = (const float*)d_in[4];
  const float* zh_b  = (const float*)d_in[5];
  const float* zx_w  = (const float*)d_in[6];
  const float* zx_b  = (const float*)d_in[7];
  const float* zb_w  = (const float*)d_in[8];
  const float* dh_w  = (const float*)d_in[9];
  const float* dx_w  = (const float*)d_in[10];
  const float* db_w  = (const float*)d_in[11];
  const float* db_b  = (const float*)d_in[12];
  const float* w_h   = (const float*)d_in[13];
  const float* w_x   = (const float*)d_in[14];
  const float* ln_w  = (const float*)d_in[15];
  const float* ln_b  = (const float*)d_in[16];

  char* ws = (char*)d_ws;
  unsigned short* h_bf    = (unsigned short*)(ws + 0);          //  4 MB
  unsigned short* x_bf    = (unsigned short*)(ws + 4194304);    //  4 MB (contig)
  unsigned short* meta_bf = (unsigned short*)(ws + 8388608);    //  1 MB
  unsigned short* Wh      = (unsigned short*)(ws + 9437184);    //  8 MB
  unsigned short* Wx      = (unsigned short*)(ws + 17825792);   //  8 MB (contig)
  unsigned short* Wd      = (unsigned short*)(ws + 26214400);   //  6 MB
  unsigned short* WzT     = (unsigned short*)(ws + 32505856);   //  1.5 MB
  unsigned short* E       = (unsigned short*)(ws + 34078720);   //  6 MB
  float*          F       = (float*)(ws + 40370176);            //  48 KB
  unsigned short* dall    = (unsigned short*)(ws + 40419328);   // 48 MB
  unsigned short* whx     = (unsigned short*)(ws + 90750976);   // 32 MB
  if (ws_size < 124305408) return;

  SegTable st;
  int i = 0, total = 0;
  auto add = [&](const float* s, unsigned short* d, int n) {
    st.src[i] = s; st.dst[i] = d; st.chunks[i] = n / 4096;
    total += n / 4096; ++i;
  };
  add(h_in, h_bf, 2048 * 1024);
  add(src_x, x_bf, 2048 * 1024);
  add(meta, meta_bf, 2048 * 256);
  add(w_h, Wh, 4096 * 1024);
  add(w_x, Wx, 4096 * 1024);
  add(dh_w, Wd, 4 * 1024 * 256);
  add(dx_w, Wd + 1048576, 4 * 1024 * 256);
  add(db_w, Wd + 2097152, 4 * 1024 * 256);
  cast_f32_bf16<<<total, 256, 0, stream>>>(st);

  // transpose-cast z-weights + exact fp32 F bias
  tcast_z<<<dim3(4, 4, 12), 256, 0, stream>>>(zh_w, zx_w, zb_w, WzT);
  fbias_kernel<<<132, 256, 0, stream>>>(zh_b, zx_b, db_b, dh_w, dx_w, F);

  // E[zz] = Wd[zz] @ WzT[zz] (NT), 12 x (1024 x 256, K=256)
  gemm_e<<<dim3(2, 8, 12), 256, 0, stream>>>(Wd, WzT, E);

  // dall = meta @ E^T + F, 12 x (2048 x 1024, K=256)
  gemm_d<<<dim3(8, 16, 12), 256, 0, stream>>>(meta_bf, E, dall, F);

  // wh/wx via 256^2 kernel (grid exactly 256 blocks)
  gemm256_whx<<<256, 512, 0, stream>>>(h_bf, Wh, whx);

  // fused LN + gates
  epilogue_kernel<<<2048, 256, 0, stream>>>(dall, whx, c_in, ln_w, ln_b,
                                            (float*)d_out);
}